// Round 8
// baseline (284.340 us; speedup 1.0000x reference)
//
#include <hip/hip_runtime.h>
#include <stdint.h>
#include <stddef.h>

#define BATCH 64
#define NN    1024
#define DD    64   // DIN == DOUT == 64
#define CTRS  32   // ints per counter slot (128 B): one cache line per batch counter

typedef _Float16 h8 __attribute__((ext_vector_type(8)));
typedef _Float16 h4 __attribute__((ext_vector_type(4)));
typedef float    f32x4 __attribute__((ext_vector_type(4)));

// XOR-swizzled granule slot: [rows][8 granules of 16B] tiles.
__device__ __forceinline__ int swz(int row, int gran) {
    return (row << 3) + (gran ^ (row & 7));
}

// ---------------- K0: weight -> WT (transposed fp16) + weight copy + ctr zero ----------
__global__ __launch_bounds__(256) void k_wt(const float* __restrict__ w,
                                            _Float16* __restrict__ wt,
                                            float* __restrict__ ow,
                                            int* __restrict__ ctr) {
#pragma unroll
    for (int z = 0; z < 8; ++z) ctr[threadIdx.x + (z << 8)] = 0;   // 64 * CTRS ints
#pragma unroll
    for (int it = 0; it < 4; ++it) {
        const int idx = threadIdx.x + (it << 8);   // float4 index 0..1023
        const int k = idx >> 4, d4 = idx & 15;
        const float4 v = ((const float4*)w)[idx];
        wt[(d4 * 4 + 0) * DD + k] = (_Float16)v.x;
        wt[(d4 * 4 + 1) * DD + k] = (_Float16)v.y;
        wt[(d4 * 4 + 2) * DD + k] = (_Float16)v.z;
        wt[(d4 * 4 + 3) * DD + k] = (_Float16)v.w;
        ((float4*)ow)[idx] = v;                     // tuple output #1: weight passthrough
    }
}

// ---------------- K1: z^T[b][d][j] = (att @ W)[j][d], fp16, UNscaled -------------------
__global__ __launch_bounds__(256) void k_xw(const float* __restrict__ att,
                                            const _Float16* __restrict__ wt,
                                            _Float16* __restrict__ zT) {
    __shared__ __align__(16) _Float16 attS[128 * 64];
    __shared__ __align__(16) _Float16 wtS[64 * 64];
    const int t = threadIdx.x;
    const int bb = blockIdx.y;
    const int j0 = blockIdx.x * 128;

#pragma unroll
    for (int it = 0; it < 4; ++it) {
        const int g = t + (it << 8);
        const int r = g >> 3, c = g & 7;
        const float4* p = (const float4*)(att + (size_t)(bb * NN + j0 + r) * DD + (c << 3));
        const float4 v0 = p[0], v1 = p[1];
        h8 o;
        o[0] = (_Float16)v0.x; o[1] = (_Float16)v0.y; o[2] = (_Float16)v0.z; o[3] = (_Float16)v0.w;
        o[4] = (_Float16)v1.x; o[5] = (_Float16)v1.y; o[6] = (_Float16)v1.z; o[7] = (_Float16)v1.w;
        *(h8*)&attS[swz(r, c) * 8] = o;
    }
#pragma unroll
    for (int it = 0; it < 2; ++it) {
        const int g = t + (it << 8);
        const int r = g >> 3, c = g & 7;
        const h8 v = *(const h8*)(wt + r * DD + (c << 3));
        *(h8*)&wtS[swz(r, c) * 8] = v;
    }
    __syncthreads();

    const int w = t >> 6, lane = t & 63;
    const int lr = lane & 15, lg = lane >> 4;
    const f32x4 zero = {0.f, 0.f, 0.f, 0.f};
    f32x4 acc[2][4];
#pragma unroll
    for (int mf = 0; mf < 2; ++mf)
#pragma unroll
        for (int nf = 0; nf < 4; ++nf) acc[mf][nf] = zero;

#pragma unroll
    for (int kk = 0; kk < 2; ++kk) {
        h8 a[2], bfr[4];
#pragma unroll
        for (int mf = 0; mf < 2; ++mf)
            a[mf] = *(const h8*)&attS[swz(w * 32 + mf * 16 + lr, kk * 4 + lg) * 8];
#pragma unroll
        for (int nf = 0; nf < 4; ++nf)
            bfr[nf] = *(const h8*)&wtS[swz(nf * 16 + lr, kk * 4 + lg) * 8];
#pragma unroll
        for (int mf = 0; mf < 2; ++mf)
#pragma unroll
            for (int nf = 0; nf < 4; ++nf)
                acc[mf][nf] = __builtin_amdgcn_mfma_f32_16x16x32_f16(a[mf], bfr[nf], acc[mf][nf], 0, 0, 0);
    }

    // D layout: col(d)=lane&15, row(j)=(lane>>4)*4+reg -> 4 consecutive j -> 8B store.
#pragma unroll
    for (int mf = 0; mf < 2; ++mf) {
        const int jb = j0 + w * 32 + mf * 16 + lg * 4;
#pragma unroll
        for (int nf = 0; nf < 4; ++nf) {
            const int d = nf * 16 + lr;
            h4 o;
            o[0] = (_Float16)acc[mf][nf][0];
            o[1] = (_Float16)acc[mf][nf][1];
            o[2] = (_Float16)acc[mf][nf][2];
            o[3] = (_Float16)acc[mf][nf][3];
            *(h4*)(zT + (size_t)(bb * DD + d) * NN + jb) = o;
        }
    }
}

// ---------------- K2: deg (own rows, cached) + 16-block barrier + aggregate ------------
// Grid 1024 = 4 blocks/CU (32 KiB LDS), all co-resident. Block x: batch bb=x&63,
// rows [i0, i0+64). Phase 1: deferred-reduce rowsums (all 64 loads schedulable in
// flight -> HBM duty cycle high) with normal cached loads so phase 2's re-read hits
// L2/L3 (proven round 7: FETCH ~= adj once). Barrier: 16 arrivals per batch.
// Phase 2: LDS double-buffer, depth-2 register prefetch (named ping-pong sets),
// ONE barrier per tile, diag (+dinv_i) folded into the staging convert.
__global__ __launch_bounds__(256, 4) void k_degagg(const float* __restrict__ adj,
                                                   const _Float16* __restrict__ zT,
                                                   float* __restrict__ dinv,
                                                   float* __restrict__ out,
                                                   int* __restrict__ ctr) {
    __shared__ __align__(16) _Float16 SA[2][64 * 64];   // adj tiles (fp16, scaled)
    __shared__ __align__(16) _Float16 SZ[2][64 * 64];   // zT tiles
    const int t = threadIdx.x;
    const int x = blockIdx.x;
    const int bb = x & 63;
    const int i0 = (x >> 6) << 6;
    const int w = t >> 6, lane = t & 63;

    // ---- phase 1: degrees of rows i0..i0+63; wave w owns rows w*16..w*16+15 ----
    {
        const int w16 = w << 4;
        const float* base = adj + ((size_t)bb * NN + i0 + w16) * NN;
        float s[16];
#pragma unroll
        for (int rr = 0; rr < 16; ++rr) {
            const float4* rp = (const float4*)(base + (size_t)rr * NN);
            const float4 v0 = rp[lane];
            const float4 v1 = rp[lane + 64];
            const float4 v2 = rp[lane + 128];
            const float4 v3 = rp[lane + 192];
            s[rr] = (v0.x + v0.y + v0.z + v0.w) + (v1.x + v1.y + v1.z + v1.w)
                  + (v2.x + v2.y + v2.z + v2.w) + (v3.x + v3.y + v3.z + v3.w);
        }
#pragma unroll
        for (int rr = 0; rr < 16; ++rr) {
            float v = s[rr];
#pragma unroll
            for (int off = 32; off; off >>= 1) v += __shfl_xor(v, off);
            if (lane == 0)
                __hip_atomic_store(dinv + bb * NN + i0 + w16 + rr, 1.f / sqrtf(v),
                                   __ATOMIC_RELAXED, __HIP_MEMORY_SCOPE_AGENT);
        }
    }
    __syncthreads();                                 // all waves' stores drained
    if (t == 0) {
        __hip_atomic_fetch_add(ctr + bb * CTRS, 1, __ATOMIC_RELEASE, __HIP_MEMORY_SCOPE_AGENT);
        while (__hip_atomic_load(ctr + bb * CTRS, __ATOMIC_RELAXED,
                                 __HIP_MEMORY_SCOPE_AGENT) < 16)
            __builtin_amdgcn_s_sleep(8);
    }
    __syncthreads();
    __threadfence();                                 // acquire: fresh dinv below

    // ---- phase 2: out rows i0..i0+63 = dinv_i * (adj+I) * dinv_j * z ----
    const int lr = lane & 15, lg = lane >> 4;
    const float* dvB = dinv + bb * NN;
    const int r0 = t >> 3, c0 = t & 7;               // slot 0: rows 0..31
    const int r1 = 32 + (t >> 3);                    // slot 1: rows 32..63
    const float dg0 = dvB[i0 + r0];
    const float dg1 = dvB[i0 + r1];

    f32x4 paA[2][2], paB[2][2];                      // ping-pong prefetch sets
    h8    pzA[2],    pzB[2];

    auto loadT = [&](f32x4 (&pa)[2][2], h8 (&pz)[2], int kt) {
        const int gj = kt * 64 + (c0 << 3);
#pragma unroll
        for (int it = 0; it < 2; ++it) {
            const int r = it ? r1 : r0;
            const f32x4* p = (const f32x4*)(adj + (size_t)(bb * NN + i0 + r) * NN + gj);
            pa[it][0] = p[0];
            pa[it][1] = p[1];
            pz[it] = *(const h8*)(zT + (size_t)(bb * DD + r) * NN + gj);
        }
    };
    auto writeT = [&](const f32x4 (&pa)[2][2], const h8 (&pz)[2],
                      _Float16* A_, _Float16* Z_, int kt) {
        const int gj = kt * 64 + (c0 << 3);
        const f32x4 d0 = *(const f32x4*)(dvB + gj);
        const f32x4 d1 = *(const f32x4*)(dvB + gj + 4);
#pragma unroll
        for (int it = 0; it < 2; ++it) {
            const int r = it ? r1 : r0;
            const int gi = i0 + r;
            const float dg = it ? dg1 : dg0;
            h8 o;
#pragma unroll
            for (int e = 0; e < 4; ++e) {
                float f = pa[it][0][e] * d0[e];
                if (gj + e == gi) f += dg;           // self-loop (implies diag tile)
                o[e] = (_Float16)f;
            }
#pragma unroll
            for (int e = 0; e < 4; ++e) {
                float f = pa[it][1][e] * d1[e];
                if (gj + 4 + e == gi) f += dg;
                o[4 + e] = (_Float16)f;
            }
            *(h8*)&A_[swz(r, c0) * 8] = o;
            *(h8*)&Z_[swz(r, c0) * 8] = pz[it];
        }
    };

    const f32x4 zero = {0.f, 0.f, 0.f, 0.f};
    f32x4 acc[4];
#pragma unroll
    for (int nf = 0; nf < 4; ++nf) acc[nf] = zero;

    auto mmaT = [&](const _Float16* A_, const _Float16* Z_) {
#pragma unroll
        for (int kk = 0; kk < 2; ++kk) {
            const h8 a = *(const h8*)&A_[swz(w * 16 + lr, kk * 4 + lg) * 8];
#pragma unroll
            for (int nf = 0; nf < 4; ++nf) {
                const h8 bz = *(const h8*)&Z_[swz(nf * 16 + lr, kk * 4 + lg) * 8];
                acc[nf] = __builtin_amdgcn_mfma_f32_16x16x32_f16(a, bz, acc[nf], 0, 0, 0);
            }
        }
    };

    loadT(paA, pzA, 0);
    loadT(paB, pzB, 1);
    writeT(paA, pzA, SA[0], SZ[0], 0);
    __syncthreads();
#pragma unroll 1
    for (int kt = 0; kt < 16; kt += 2) {
        if (kt + 2 < 16) loadT(paA, pzA, kt + 2);    // in flight across MFMA+write+sync
        mmaT(SA[0], SZ[0]);                          // tile kt
        writeT(paB, pzB, SA[1], SZ[1], kt + 1);      // tile kt+1 -> other buffer
        __syncthreads();
        if (kt + 3 < 16) loadT(paB, pzB, kt + 3);
        mmaT(SA[1], SZ[1]);                          // tile kt+1
        if (kt + 2 < 16) writeT(paA, pzA, SA[0], SZ[0], kt + 2);
        __syncthreads();
    }

    const int ib = i0 + w * 16 + lg * 4;             // 4 consecutive output rows
    const float4 dv = *(const float4*)&dvB[ib];
#pragma unroll
    for (int nf = 0; nf < 4; ++nf) {
        const int d = nf * 16 + lr;
        float* op = out + ((size_t)bb * NN + ib) * DD + d;
        __builtin_nontemporal_store(acc[nf][0] * dv.x, op + 0 * DD);
        __builtin_nontemporal_store(acc[nf][1] * dv.y, op + 1 * DD);
        __builtin_nontemporal_store(acc[nf][2] * dv.z, op + 2 * DD);
        __builtin_nontemporal_store(acc[nf][3] * dv.w, op + 3 * DD);
    }
}

extern "C" void kernel_launch(void* const* d_in, const int* in_sizes, int n_in,
                              void* d_out, int out_size, void* d_ws, size_t ws_size,
                              hipStream_t stream) {
    const float* adj = (const float*)d_in[0];
    const float* att = (const float*)d_in[1];
    const float* wgt = (const float*)d_in[2];
    float* out = (float*)d_out;
    char* ws = (char*)d_ws;

    size_t off = 0;
    _Float16* zT  = (_Float16*)(ws + off); off += (size_t)BATCH * DD * NN * 2;  // 8 MiB
    float*    dinv = (float*)(ws + off);   off += (size_t)BATCH * NN * 4;       // 256 KiB
    _Float16* wt  = (_Float16*)(ws + off); off += (size_t)DD * DD * 2;          // 8 KiB
    int*      ctr = (int*)(ws + off);                                           // 8 KiB

    k_wt<<<1, 256, 0, stream>>>(wgt, wt, out + (size_t)BATCH * NN * DD, ctr);
    k_xw<<<dim3(NN / 128, BATCH), 256, 0, stream>>>(att, wt, zT);
    k_degagg<<<BATCH * (NN / 64), 256, 0, stream>>>(adj, zT, dinv, out, ctr);
}

// Round 9
// 214.142 us; speedup vs baseline: 1.3278x; 1.3278x over previous
//
#include <hip/hip_runtime.h>
#include <stdint.h>
#include <stddef.h>

#define BATCH 64
#define NN    1024
#define DD    64   // DIN == DOUT == 64
#define CTRS  32   // ints per counter slot (128 B): one cache line per batch counter

typedef _Float16 h8 __attribute__((ext_vector_type(8)));
typedef _Float16 h4 __attribute__((ext_vector_type(4)));
typedef float    f32x4 __attribute__((ext_vector_type(4)));

// XOR-swizzled granule slot: [rows][8 granules of 16B] tiles.
__device__ __forceinline__ int swz(int row, int gran) {
    return (row << 3) + (gran ^ (row & 7));
}

// ---------------- K0: weight -> WT (transposed fp16) + weight copy + ctr zero ----------
__global__ __launch_bounds__(256) void k_wt(const float* __restrict__ w,
                                            _Float16* __restrict__ wt,
                                            float* __restrict__ ow,
                                            int* __restrict__ ctr) {
#pragma unroll
    for (int z = 0; z < 8; ++z) ctr[threadIdx.x + (z << 8)] = 0;   // 64 * CTRS ints
#pragma unroll
    for (int it = 0; it < 4; ++it) {
        const int idx = threadIdx.x + (it << 8);   // float4 index 0..1023
        const int k = idx >> 4, d4 = idx & 15;
        const float4 v = ((const float4*)w)[idx];
        wt[(d4 * 4 + 0) * DD + k] = (_Float16)v.x;
        wt[(d4 * 4 + 1) * DD + k] = (_Float16)v.y;
        wt[(d4 * 4 + 2) * DD + k] = (_Float16)v.z;
        wt[(d4 * 4 + 3) * DD + k] = (_Float16)v.w;
        ((float4*)ow)[idx] = v;                     // tuple output #1: weight passthrough
    }
}

// ---------------- K1: z^T[b][d][j] = (att @ W)[j][d], fp16, UNscaled -------------------
__global__ __launch_bounds__(256) void k_xw(const float* __restrict__ att,
                                            const _Float16* __restrict__ wt,
                                            _Float16* __restrict__ zT) {
    __shared__ __align__(16) _Float16 attS[128 * 64];
    __shared__ __align__(16) _Float16 wtS[64 * 64];
    const int t = threadIdx.x;
    const int bb = blockIdx.y;
    const int j0 = blockIdx.x * 128;

#pragma unroll
    for (int it = 0; it < 4; ++it) {
        const int g = t + (it << 8);
        const int r = g >> 3, c = g & 7;
        const float4* p = (const float4*)(att + (size_t)(bb * NN + j0 + r) * DD + (c << 3));
        const float4 v0 = p[0], v1 = p[1];
        h8 o;
        o[0] = (_Float16)v0.x; o[1] = (_Float16)v0.y; o[2] = (_Float16)v0.z; o[3] = (_Float16)v0.w;
        o[4] = (_Float16)v1.x; o[5] = (_Float16)v1.y; o[6] = (_Float16)v1.z; o[7] = (_Float16)v1.w;
        *(h8*)&attS[swz(r, c) * 8] = o;
    }
#pragma unroll
    for (int it = 0; it < 2; ++it) {
        const int g = t + (it << 8);
        const int r = g >> 3, c = g & 7;
        const h8 v = *(const h8*)(wt + r * DD + (c << 3));
        *(h8*)&wtS[swz(r, c) * 8] = v;
    }
    __syncthreads();

    const int w = t >> 6, lane = t & 63;
    const int lr = lane & 15, lg = lane >> 4;
    const f32x4 zero = {0.f, 0.f, 0.f, 0.f};
    f32x4 acc[2][4];
#pragma unroll
    for (int mf = 0; mf < 2; ++mf)
#pragma unroll
        for (int nf = 0; nf < 4; ++nf) acc[mf][nf] = zero;

#pragma unroll
    for (int kk = 0; kk < 2; ++kk) {
        h8 a[2], bfr[4];
#pragma unroll
        for (int mf = 0; mf < 2; ++mf)
            a[mf] = *(const h8*)&attS[swz(w * 32 + mf * 16 + lr, kk * 4 + lg) * 8];
#pragma unroll
        for (int nf = 0; nf < 4; ++nf)
            bfr[nf] = *(const h8*)&wtS[swz(nf * 16 + lr, kk * 4 + lg) * 8];
#pragma unroll
        for (int mf = 0; mf < 2; ++mf)
#pragma unroll
            for (int nf = 0; nf < 4; ++nf)
                acc[mf][nf] = __builtin_amdgcn_mfma_f32_16x16x32_f16(a[mf], bfr[nf], acc[mf][nf], 0, 0, 0);
    }

    // D layout: col(d)=lane&15, row(j)=(lane>>4)*4+reg -> 4 consecutive j -> 8B store.
#pragma unroll
    for (int mf = 0; mf < 2; ++mf) {
        const int jb = j0 + w * 32 + mf * 16 + lg * 4;
#pragma unroll
        for (int nf = 0; nf < 4; ++nf) {
            const int d = nf * 16 + lr;
            h4 o;
            o[0] = (_Float16)acc[mf][nf][0];
            o[1] = (_Float16)acc[mf][nf][1];
            o[2] = (_Float16)acc[mf][nf][2];
            o[3] = (_Float16)acc[mf][nf][3];
            *(h4*)(zT + (size_t)(bb * DD + d) * NN + jb) = o;
        }
    }
}

// Barrier that does NOT drain vmcnt: prefetch global loads stay in flight (T4).
#define BARNV() do {                                          \
    __builtin_amdgcn_sched_barrier(0);                        \
    asm volatile("s_waitcnt lgkmcnt(0)" ::: "memory");        \
    __builtin_amdgcn_s_barrier();                             \
    __builtin_amdgcn_sched_barrier(0);                        \
} while (0)

// Prefetch one 64x64 tile into named registers (6 global loads, stay in flight).
#define LOADT(P, kt) do {                                                             \
    const int gj = (kt) * 64 + (c0 << 3);                                             \
    const f32x4* p0_ = (const f32x4*)(adj + (size_t)(bb * NN + i0 + r0) * NN + gj);   \
    P##a00 = p0_[0]; P##a01 = p0_[1];                                                 \
    const f32x4* p1_ = (const f32x4*)(adj + (size_t)(bb * NN + i0 + r1) * NN + gj);   \
    P##a10 = p1_[0]; P##a11 = p1_[1];                                                 \
    P##z0 = *(const h8*)(zT + (size_t)(bb * DD + r0) * NN + gj);                      \
    P##z1 = *(const h8*)(zT + (size_t)(bb * DD + r1) * NN + gj);                      \
} while (0)

// Convert+scale prefetched tile into LDS (dinv_j fold + self-loop on diagonal).
#define WRITET(P, kt, A_, Z_) do {                                                    \
    const int gj = (kt) * 64 + (c0 << 3);                                             \
    const f32x4 d0_ = *(const f32x4*)(dvB + gj);                                      \
    const f32x4 d1_ = *(const f32x4*)(dvB + gj + 4);                                  \
    h8 o0_, o1_;                                                                      \
    _Pragma("unroll") for (int e = 0; e < 4; ++e) {                                   \
        float f0 = P##a00[e] * d0_[e];                                                \
        if (gj + e == i0 + r0) f0 += dg0;                                             \
        o0_[e] = (_Float16)f0;                                                        \
        float f1 = P##a01[e] * d1_[e];                                                \
        if (gj + 4 + e == i0 + r0) f1 += dg0;                                         \
        o0_[4 + e] = (_Float16)f1;                                                    \
        float f2 = P##a10[e] * d0_[e];                                                \
        if (gj + e == i0 + r1) f2 += dg1;                                             \
        o1_[e] = (_Float16)f2;                                                        \
        float f3 = P##a11[e] * d1_[e];                                                \
        if (gj + 4 + e == i0 + r1) f3 += dg1;                                         \
        o1_[4 + e] = (_Float16)f3;                                                    \
    }                                                                                 \
    *(h8*)&(A_)[swz(r0, c0) * 8] = o0_;                                               \
    *(h8*)&(Z_)[swz(r0, c0) * 8] = P##z0;                                             \
    *(h8*)&(A_)[swz(r1, c0) * 8] = o1_;                                               \
    *(h8*)&(Z_)[swz(r1, c0) * 8] = P##z1;                                             \
} while (0)

#define MMAT(A_, Z_) do {                                                             \
    _Pragma("unroll") for (int kk = 0; kk < 2; ++kk) {                                \
        const h8 a_ = *(const h8*)&(A_)[swz(w * 16 + lr, kk * 4 + lg) * 8];           \
        _Pragma("unroll") for (int nf = 0; nf < 4; ++nf) {                            \
            const h8 bz_ = *(const h8*)&(Z_)[swz(nf * 16 + lr, kk * 4 + lg) * 8];     \
            acc[nf] = __builtin_amdgcn_mfma_f32_16x16x32_f16(a_, bz_, acc[nf], 0, 0, 0); \
        }                                                                             \
    }                                                                                 \
} while (0)

// ---------------- K2: deg (own rows, cached) + 16-block barrier + aggregate ------------
// Grid 1024 = 4 blocks/CU (32 KiB LDS). Phase 1: cached rowsum stream (leaves adj in
// L2/L3 for phase 2's re-read -- proven r7: FETCH ~= adj once). Phase 2: depth-2
// register prefetch in NAMED regs (r8 spill lesson), double-buffered LDS, one
// NON-DRAINING barrier per tile (counted vmcnt across s_barrier, T4).
__global__ __launch_bounds__(256, 4) void k_degagg(const float* __restrict__ adj,
                                                   const _Float16* __restrict__ zT,
                                                   float* __restrict__ dinv,
                                                   float* __restrict__ out,
                                                   int* __restrict__ ctr) {
    __shared__ __align__(16) _Float16 SA0[64 * 64], SA1[64 * 64];
    __shared__ __align__(16) _Float16 SZ0[64 * 64], SZ1[64 * 64];
    const int t = threadIdx.x;
    const int x = blockIdx.x;
    const int bb = x & 63;
    const int i0 = (x >> 6) << 6;
    const int w = t >> 6, lane = t & 63;

    // ---- phase 1: degrees of rows i0..i0+63; wave w owns 16 rows, 2 at a time ----
    {
        const int w16 = w << 4;
        const float* base = adj + ((size_t)bb * NN + i0 + w16) * NN;
#pragma unroll 1
        for (int rp = 0; rp < 8; ++rp) {
            const float4* ra = (const float4*)(base + (size_t)(2 * rp) * NN);
            const float4* rb = (const float4*)(base + (size_t)(2 * rp + 1) * NN);
            const float4 a0 = ra[lane], a1 = ra[lane + 64], a2 = ra[lane + 128], a3 = ra[lane + 192];
            const float4 b0 = rb[lane], b1 = rb[lane + 64], b2 = rb[lane + 128], b3 = rb[lane + 192];
            float sa = (a0.x + a0.y + a0.z + a0.w) + (a1.x + a1.y + a1.z + a1.w)
                     + (a2.x + a2.y + a2.z + a2.w) + (a3.x + a3.y + a3.z + a3.w);
            float sb = (b0.x + b0.y + b0.z + b0.w) + (b1.x + b1.y + b1.z + b1.w)
                     + (b2.x + b2.y + b2.z + b2.w) + (b3.x + b3.y + b3.z + b3.w);
#pragma unroll
            for (int off = 32; off; off >>= 1) {   // two independent chains
                sa += __shfl_xor(sa, off);
                sb += __shfl_xor(sb, off);
            }
            if (lane == 0) {
                __hip_atomic_store(dinv + bb * NN + i0 + w16 + 2 * rp, 1.f / sqrtf(sa),
                                   __ATOMIC_RELAXED, __HIP_MEMORY_SCOPE_AGENT);
                __hip_atomic_store(dinv + bb * NN + i0 + w16 + 2 * rp + 1, 1.f / sqrtf(sb),
                                   __ATOMIC_RELAXED, __HIP_MEMORY_SCOPE_AGENT);
            }
        }
    }
    __syncthreads();                                 // all waves' stores drained
    if (t == 0) {
        __hip_atomic_fetch_add(ctr + bb * CTRS, 1, __ATOMIC_RELEASE, __HIP_MEMORY_SCOPE_AGENT);
        while (__hip_atomic_load(ctr + bb * CTRS, __ATOMIC_RELAXED,
                                 __HIP_MEMORY_SCOPE_AGENT) < 16)
            __builtin_amdgcn_s_sleep(8);
    }
    __syncthreads();
    __threadfence();                                 // acquire: fresh dinv below

    // ---- phase 2: out rows i0..i0+63 = dinv_i * (adj+I) * dinv_j * z ----
    const int lr = lane & 15, lg = lane >> 4;
    const float* dvB = dinv + bb * NN;
    const int r0 = t >> 3, c0 = t & 7;               // rows 0..31
    const int r1 = 32 + (t >> 3);                    // rows 32..63
    const float dg0 = dvB[i0 + r0];
    const float dg1 = dvB[i0 + r1];

    f32x4 Aa00, Aa01, Aa10, Aa11;  h8 Az0, Az1;      // named prefetch set A
    f32x4 Ba00, Ba01, Ba10, Ba11;  h8 Bz0, Bz1;      // named prefetch set B

    const f32x4 zero = {0.f, 0.f, 0.f, 0.f};
    f32x4 acc[4];
#pragma unroll
    for (int nf = 0; nf < 4; ++nf) acc[nf] = zero;

    LOADT(A, 0);
    LOADT(B, 1);
    WRITET(A, 0, SA0, SZ0);
    BARNV();
#pragma unroll 1
    for (int kt = 0; kt < 16; kt += 2) {
        if (kt + 2 < 16) LOADT(A, kt + 2);           // in flight across barriers
        MMAT(SA0, SZ0);                              // tile kt
        WRITET(B, kt + 1, SA1, SZ1);
        BARNV();
        if (kt + 3 < 16) LOADT(B, kt + 3);
        MMAT(SA1, SZ1);                              // tile kt+1
        if (kt + 2 < 16) WRITET(A, kt + 2, SA0, SZ0);
        BARNV();
    }

    const int ib = i0 + w * 16 + lg * 4;             // 4 consecutive output rows
    const float4 dv = *(const float4*)&dvB[ib];
#pragma unroll
    for (int nf = 0; nf < 4; ++nf) {
        const int d = nf * 16 + lr;
        float* op = out + ((size_t)bb * NN + ib) * DD + d;
        __builtin_nontemporal_store(acc[nf][0] * dv.x, op + 0 * DD);
        __builtin_nontemporal_store(acc[nf][1] * dv.y, op + 1 * DD);
        __builtin_nontemporal_store(acc[nf][2] * dv.z, op + 2 * DD);
        __builtin_nontemporal_store(acc[nf][3] * dv.w, op + 3 * DD);
    }
}

extern "C" void kernel_launch(void* const* d_in, const int* in_sizes, int n_in,
                              void* d_out, int out_size, void* d_ws, size_t ws_size,
                              hipStream_t stream) {
    const float* adj = (const float*)d_in[0];
    const float* att = (const float*)d_in[1];
    const float* wgt = (const float*)d_in[2];
    float* out = (float*)d_out;
    char* ws = (char*)d_ws;

    size_t off = 0;
    _Float16* zT  = (_Float16*)(ws + off); off += (size_t)BATCH * DD * NN * 2;  // 8 MiB
    float*    dinv = (float*)(ws + off);   off += (size_t)BATCH * NN * 4;       // 256 KiB
    _Float16* wt  = (_Float16*)(ws + off); off += (size_t)DD * DD * 2;          // 8 KiB
    int*      ctr = (int*)(ws + off);                                           // 8 KiB

    k_wt<<<1, 256, 0, stream>>>(wgt, wt, out + (size_t)BATCH * NN * DD, ctr);
    k_xw<<<dim3(NN / 128, BATCH), 256, 0, stream>>>(att, wt, zT);
    k_degagg<<<BATCH * (NN / 64), 256, 0, stream>>>(adj, zT, dinv, out, ctr);
}

// Round 10
// 102.619 us; speedup vs baseline: 2.7708x; 2.0868x over previous
//
#include <hip/hip_runtime.h>
#include <stdint.h>
#include <stddef.h>

#define BATCH 64
#define NN    1024
#define DD    64            // DIN == DOUT == 64
#define XWB   512           // xw blocks at the head of the merged grid (dispatch first)
#define DEGB  (BATCH * NN / 4)

typedef _Float16 h8 __attribute__((ext_vector_type(8)));
typedef _Float16 h4 __attribute__((ext_vector_type(4)));
typedef float    f32x4 __attribute__((ext_vector_type(4)));

// XOR-swizzled granule slot: [rows][8 granules of 16B] tiles.
__device__ __forceinline__ int swz(int row, int gran) {
    return (row << 3) + (gran ^ (row & 7));
}

// ---------------- K1: heterogeneous deg + xw (+ weight passthrough) --------------------
// Blocks [0, XWB): zT[b][d][j] = (att @ W)[j][d] fp16 UNscaled (W transposed in-LDS
//   from fp32, no global wt buffer; block 0 also copies weight to the output tail).
// Blocks [XWB, XWB+DEGB): row-degree streams, 1 row/wave -> dinv. Plain stores;
//   visibility to k_agg via the kernel boundary. No cross-block communication.
__global__ __launch_bounds__(256) void k_degxw(const float* __restrict__ adj,
                                               const float* __restrict__ att,
                                               const float* __restrict__ wgt,
                                               _Float16* __restrict__ zT,
                                               float* __restrict__ dinv,
                                               float* __restrict__ ow) {
    __shared__ __align__(16) _Float16 attS[128 * 64];
    __shared__ __align__(16) _Float16 wtS[64 * 64];
    const int t = threadIdx.x;
    const int x = blockIdx.x;

    if (x >= XWB) {
        // ---- deg branch: one row per wave ----
        const int lane = t & 63;
        const int rowg = (x - XWB) * 4 + (t >> 6);
        const float* rp = adj + (size_t)rowg * NN;
        float s = 0.f;
#pragma unroll
        for (int k = 0; k < 4; ++k) {
            const float4 v = ((const float4*)rp)[lane + (k << 6)];
            s += v.x + v.y + v.z + v.w;
        }
#pragma unroll
        for (int off = 32; off; off >>= 1) s += __shfl_xor(s, off);
        if (lane == 0) dinv[rowg] = 1.f / sqrtf(s);
        return;
    }

    // ---- xw branch: batch bb, 128-row j-tile ----
    const int bb = x >> 3;
    const int j0 = (x & 7) * 128;
    if (x == 0) {                                    // tuple output #1: weight copy
#pragma unroll
        for (int it = 0; it < 4; ++it) {
            const int idx = t + (it << 8);
            ((float4*)ow)[idx] = ((const float4*)wgt)[idx];
        }
    }
    // stage att tile (fp32 -> fp16)
#pragma unroll
    for (int it = 0; it < 4; ++it) {
        const int g = t + (it << 8);
        const int r = g >> 3, c = g & 7;
        const float4* p = (const float4*)(att + (size_t)(bb * NN + j0 + r) * DD + (c << 3));
        const float4 v0 = p[0], v1 = p[1];
        h8 o;
        o[0] = (_Float16)v0.x; o[1] = (_Float16)v0.y; o[2] = (_Float16)v0.z; o[3] = (_Float16)v0.w;
        o[4] = (_Float16)v1.x; o[5] = (_Float16)v1.y; o[6] = (_Float16)v1.z; o[7] = (_Float16)v1.w;
        *(h8*)&attS[swz(r, c) * 8] = o;
    }
    // stage W^T (fp32 w[k][d] -> wtS[d][k] fp16, scattered half writes; one-time cost)
#pragma unroll
    for (int it = 0; it < 4; ++it) {
        const int idx = t + (it << 8);               // float4 id 0..1023
        const int k = idx >> 4, d4 = (idx & 15) << 2;
        const float4 v = ((const float4*)wgt)[idx];
        wtS[swz(d4 + 0, k >> 3) * 8 + (k & 7)] = (_Float16)v.x;
        wtS[swz(d4 + 1, k >> 3) * 8 + (k & 7)] = (_Float16)v.y;
        wtS[swz(d4 + 2, k >> 3) * 8 + (k & 7)] = (_Float16)v.z;
        wtS[swz(d4 + 3, k >> 3) * 8 + (k & 7)] = (_Float16)v.w;
    }
    __syncthreads();

    const int w = t >> 6, lane = t & 63;
    const int lr = lane & 15, lg = lane >> 4;
    const f32x4 zero = {0.f, 0.f, 0.f, 0.f};
    f32x4 acc[2][4];
#pragma unroll
    for (int mf = 0; mf < 2; ++mf)
#pragma unroll
        for (int nf = 0; nf < 4; ++nf) acc[mf][nf] = zero;

#pragma unroll
    for (int kk = 0; kk < 2; ++kk) {
        h8 a[2], bfr[4];
#pragma unroll
        for (int mf = 0; mf < 2; ++mf)
            a[mf] = *(const h8*)&attS[swz(w * 32 + mf * 16 + lr, kk * 4 + lg) * 8];
#pragma unroll
        for (int nf = 0; nf < 4; ++nf)
            bfr[nf] = *(const h8*)&wtS[swz(nf * 16 + lr, kk * 4 + lg) * 8];
#pragma unroll
        for (int mf = 0; mf < 2; ++mf)
#pragma unroll
            for (int nf = 0; nf < 4; ++nf)
                acc[mf][nf] = __builtin_amdgcn_mfma_f32_16x16x32_f16(a[mf], bfr[nf], acc[mf][nf], 0, 0, 0);
    }

    // D layout: col(d)=lane&15, row(j)=(lane>>4)*4+reg -> 4 consecutive j -> 8B store.
#pragma unroll
    for (int mf = 0; mf < 2; ++mf) {
        const int jb = j0 + w * 32 + mf * 16 + lg * 4;
#pragma unroll
        for (int nf = 0; nf < 4; ++nf) {
            const int d = nf * 16 + lr;
            h4 o;
            o[0] = (_Float16)acc[mf][nf][0];
            o[1] = (_Float16)acc[mf][nf][1];
            o[2] = (_Float16)acc[mf][nf][2];
            o[3] = (_Float16)acc[mf][nf][3];
            *(h4*)(zT + (size_t)(bb * DD + d) * NN + jb) = o;
        }
    }
}

// Barrier that does NOT drain vmcnt: prefetch global loads stay in flight (T4).
#define BARNV() do {                                          \
    __builtin_amdgcn_sched_barrier(0);                        \
    asm volatile("s_waitcnt lgkmcnt(0)" ::: "memory");        \
    __builtin_amdgcn_s_barrier();                             \
    __builtin_amdgcn_sched_barrier(0);                        \
} while (0)

// Prefetch one 64x64 tile into named registers (6 global loads, stay in flight).
#define LOADT(P, kt) do {                                                             \
    const int gj = (kt) * 64 + (c0 << 3);                                             \
    const f32x4* p0_ = (const f32x4*)(adj + (size_t)(bb * NN + i0 + r0) * NN + gj);   \
    P##a00 = p0_[0]; P##a01 = p0_[1];                                                 \
    const f32x4* p1_ = (const f32x4*)(adj + (size_t)(bb * NN + i0 + r1) * NN + gj);   \
    P##a10 = p1_[0]; P##a11 = p1_[1];                                                 \
    P##z0 = *(const h8*)(zT + (size_t)(bb * DD + r0) * NN + gj);                      \
    P##z1 = *(const h8*)(zT + (size_t)(bb * DD + r1) * NN + gj);                      \
} while (0)

// Stage prefetched tile: A = raw adj fp16 (no diag, no scale); Z = dinv_j * z.
#define WRITET(P, kt, A_, Z_) do {                                                    \
    const int gj = (kt) * 64 + (c0 << 3);                                             \
    const f32x4 d0_ = *(const f32x4*)(dvB + gj);                                      \
    const f32x4 d1_ = *(const f32x4*)(dvB + gj + 4);                                  \
    h8 a0_, a1_, z0_, z1_;                                                            \
    _Pragma("unroll") for (int e = 0; e < 4; ++e) {                                   \
        a0_[e]     = (_Float16)P##a00[e];                                             \
        a0_[4 + e] = (_Float16)P##a01[e];                                             \
        a1_[e]     = (_Float16)P##a10[e];                                             \
        a1_[4 + e] = (_Float16)P##a11[e];                                             \
        z0_[e]     = (_Float16)((float)P##z0[e]     * d0_[e]);                        \
        z0_[4 + e] = (_Float16)((float)P##z0[4 + e] * d1_[e]);                        \
        z1_[e]     = (_Float16)((float)P##z1[e]     * d0_[e]);                        \
        z1_[4 + e] = (_Float16)((float)P##z1[4 + e] * d1_[e]);                        \
    }                                                                                 \
    *(h8*)&(A_)[swz(r0, c0) * 8] = a0_;                                               \
    *(h8*)&(A_)[swz(r1, c0) * 8] = a1_;                                               \
    *(h8*)&(Z_)[swz(r0, c0) * 8] = z0_;                                               \
    *(h8*)&(Z_)[swz(r1, c0) * 8] = z1_;                                               \
} while (0)

#define MMAT(A_, Z_) do {                                                             \
    _Pragma("unroll") for (int kk = 0; kk < 2; ++kk) {                                \
        const h8 a_ = *(const h8*)&(A_)[swz(w * 16 + lr, kk * 4 + lg) * 8];           \
        _Pragma("unroll") for (int nf = 0; nf < 4; ++nf) {                            \
            const h8 bz_ = *(const h8*)&(Z_)[swz(nf * 16 + lr, kk * 4 + lg) * 8];     \
            acc[nf] = __builtin_amdgcn_mfma_f32_16x16x32_f16(a_, bz_, acc[nf], 0, 0, 0); \
        }                                                                             \
    }                                                                                 \
} while (0)

// ---------------- K2: out[b][i][d] = dinv_i * (sum_j adj_ij * dinv_j * z[j][d] + dinv_i*z[i][d])
// Pure streaming (adj re-read from HBM -- measured FASTER than L3-reuse designs, r7/r9).
// Depth-2 named-reg prefetch, double-buffered LDS, one non-draining barrier per tile.
// Self-loop handled in the epilogue: no diag fixup, no dinv-A traffic in the loop.
__global__ __launch_bounds__(256, 4) void k_agg(const float* __restrict__ adj,
                                                const _Float16* __restrict__ zT,
                                                const float* __restrict__ dinv,
                                                float* __restrict__ out) {
    __shared__ __align__(16) _Float16 SA0[64 * 64], SA1[64 * 64];
    __shared__ __align__(16) _Float16 SZ0[64 * 64], SZ1[64 * 64];
    const int t = threadIdx.x;
    const int bb = blockIdx.y;
    const int i0 = blockIdx.x << 6;
    const int w = t >> 6, lane = t & 63;
    const int lr = lane & 15, lg = lane >> 4;
    const float* dvB = dinv + bb * NN;
    const int r0 = t >> 3, c0 = t & 7;               // staging rows 0..31
    const int r1 = 32 + (t >> 3);                    // staging rows 32..63

    f32x4 Aa00, Aa01, Aa10, Aa11;  h8 Az0, Az1;      // named prefetch set A
    f32x4 Ba00, Ba01, Ba10, Ba11;  h8 Bz0, Bz1;      // named prefetch set B

    const f32x4 zero = {0.f, 0.f, 0.f, 0.f};
    f32x4 acc[4];
#pragma unroll
    for (int nf = 0; nf < 4; ++nf) acc[nf] = zero;

    LOADT(A, 0);
    LOADT(B, 1);
    WRITET(A, 0, SA0, SZ0);
    BARNV();
#pragma unroll 1
    for (int kt = 0; kt < 16; kt += 2) {
        if (kt + 2 < 16) LOADT(A, kt + 2);           // in flight across barriers
        MMAT(SA0, SZ0);                              // tile kt
        WRITET(B, kt + 1, SA1, SZ1);
        BARNV();
        if (kt + 3 < 16) LOADT(B, kt + 3);
        MMAT(SA1, SZ1);                              // tile kt+1
        if (kt + 2 < 16) WRITET(A, kt + 2, SA0, SZ0);
        BARNV();
    }

    // epilogue: out = dinv_i * (acc + dinv_i * z_i[d]); 4 consecutive output rows.
    const int ib = i0 + w * 16 + lg * 4;
    const float4 dv = *(const float4*)&dvB[ib];
#pragma unroll
    for (int nf = 0; nf < 4; ++nf) {
        const int d = nf * 16 + lr;
        const h4 zv = *(const h4*)(zT + ((size_t)bb * DD + d) * NN + ib);
        float* op = out + ((size_t)bb * NN + ib) * DD + d;
        __builtin_nontemporal_store(dv.x * (acc[nf][0] + dv.x * (float)zv[0]), op + 0 * DD);
        __builtin_nontemporal_store(dv.y * (acc[nf][1] + dv.y * (float)zv[1]), op + 1 * DD);
        __builtin_nontemporal_store(dv.z * (acc[nf][2] + dv.z * (float)zv[2]), op + 2 * DD);
        __builtin_nontemporal_store(dv.w * (acc[nf][3] + dv.w * (float)zv[3]), op + 3 * DD);
    }
}

extern "C" void kernel_launch(void* const* d_in, const int* in_sizes, int n_in,
                              void* d_out, int out_size, void* d_ws, size_t ws_size,
                              hipStream_t stream) {
    const float* adj = (const float*)d_in[0];
    const float* att = (const float*)d_in[1];
    const float* wgt = (const float*)d_in[2];
    float* out = (float*)d_out;
    char* ws = (char*)d_ws;

    size_t off = 0;
    _Float16* zT  = (_Float16*)(ws + off); off += (size_t)BATCH * DD * NN * 2;  // 8 MiB
    float*    dinv = (float*)(ws + off);                                        // 256 KiB

    k_degxw<<<XWB + DEGB, 256, 0, stream>>>(adj, att, wgt, zT, dinv,
                                            out + (size_t)BATCH * NN * DD);
    k_agg<<<dim3(NN / 64, BATCH), 256, 0, stream>>>(adj, zT, dinv, out);
}